// Round 2
// baseline (104.053 us; speedup 1.0000x reference)
//
#include <hip/hip_runtime.h>

// Dust: zero out pixels inside any of 100 small circles per image.
// img: (N=16, C=3, H=512, W=512) fp32; centers/radii: (N, A=100) int32.
//
// Block = one (image, 8-row stripe): 16*64 = 1024 blocks x 256 threads.
// Circles culled by row range into LDS (avg ~3.7 of 100 survive).
// Each thread owns a fixed column-quad (col4 = tid & 127) across 4 rows
// (rows r0, r0+2, r0+4, r0+6 with r0 = tid >> 7), so:
//   - all 12 float4 loads (4 rows x 3 channels) are issued before any use
//     (max memory-level parallelism, fully unrolled compile-time loop);
//   - per circle, the 4 dx^2 terms are computed ONCE and reused across the
//     4 rows (only dy changes) -> ~9 VALU ops per quad per circle.

#define H_DIM 512
#define W_DIM 512
#define N_IMG 16
#define C_DIM 3
#define A_CIR 100
#define ROWS_PER_BLK 8
#define THREADS 256
#define ITERS 4   // (ROWS_PER_BLK * W_DIM / 4) / THREADS

__global__ __launch_bounds__(THREADS) void dust_kernel(
    const float* __restrict__ img,
    const int* __restrict__ cy_g,
    const int* __restrict__ cx_g,
    const int* __restrict__ r_g,
    float* __restrict__ out)
{
    __shared__ int s_cy[A_CIR];
    __shared__ int s_cx[A_CIR];
    __shared__ int s_r2[A_CIR];
    __shared__ int s_cnt;

    const int tiles_per_img = H_DIM / ROWS_PER_BLK;      // 64
    const int n  = blockIdx.x / tiles_per_img;
    const int y0 = (blockIdx.x % tiles_per_img) * ROWS_PER_BLK;

    if (threadIdx.x == 0) s_cnt = 0;
    __syncthreads();

    // Row-range cull: keep circles whose [cy-r, cy+r] overlaps the stripe.
    if (threadIdx.x < A_CIR) {
        const int cy = cy_g[n * A_CIR + threadIdx.x];
        const int cx = cx_g[n * A_CIR + threadIdx.x];
        const int r  = r_g [n * A_CIR + threadIdx.x];
        if (cy + r >= y0 && cy - r <= y0 + ROWS_PER_BLK - 1) {
            const int idx = atomicAdd(&s_cnt, 1);
            s_cy[idx] = cy;
            s_cx[idx] = cx;
            s_r2[idx] = r * r;
        }
    }
    __syncthreads();
    const int cnt = s_cnt;

    // Fixed column-quad per thread; rows r0 + 2*it.
    const int r0   = threadIdx.x >> 7;                   // 0 or 1
    const int col4 = threadIdx.x & 127;
    const int w    = col4 * 4;
    const int hbase = y0 + r0;

    const size_t chan4 = (size_t)(H_DIM * W_DIM / 4);    // 65536
    const size_t base4 = (size_t)n * C_DIM * chan4
                       + (size_t)hbase * (W_DIM / 4) + col4;

    const float4* __restrict__ img4 = (const float4*)img;
    float4* __restrict__ out4 = (float4*)out;

    // Phase 1: issue ALL 12 loads (4 rows x 3 channels) before any use.
    float4 v[ITERS][C_DIM];
    #pragma unroll
    for (int it = 0; it < ITERS; ++it) {
        const size_t idx = base4 + (size_t)(2 * it) * (W_DIM / 4);
        #pragma unroll
        for (int c = 0; c < C_DIM; ++c)
            v[it][c] = img4[idx + (size_t)c * chan4];
    }

    // Phase 2: masks for all 4 rows; dx^2 terms hoisted per circle.
    unsigned mask[ITERS] = {0u, 0u, 0u, 0u};
    for (int i = 0; i < cnt; ++i) {
        const int cy = s_cy[i];
        const int r2 = s_r2[i];
        const int dx = w - s_cx[i];
        const int a0 = dx * dx;
        const int a1 = (dx + 1) * (dx + 1);
        const int a2 = (dx + 2) * (dx + 2);
        const int a3 = (dx + 3) * (dx + 3);
        #pragma unroll
        for (int it = 0; it < ITERS; ++it) {
            const int dy = hbase + 2 * it - cy;
            const int d2 = dy * dy;
            mask[it] |= (d2 + a0 <= r2 ? 1u : 0u)
                      | (d2 + a1 <= r2 ? 2u : 0u)
                      | (d2 + a2 <= r2 ? 4u : 0u)
                      | (d2 + a3 <= r2 ? 8u : 0u);
        }
    }

    // Phase 3: apply masks, store.
    #pragma unroll
    for (int it = 0; it < ITERS; ++it) {
        const size_t idx = base4 + (size_t)(2 * it) * (W_DIM / 4);
        const unsigned m = mask[it];
        #pragma unroll
        for (int c = 0; c < C_DIM; ++c) {
            float4 t = v[it][c];
            if (m & 1u) t.x = 0.0f;
            if (m & 2u) t.y = 0.0f;
            if (m & 4u) t.z = 0.0f;
            if (m & 8u) t.w = 0.0f;
            out4[idx + (size_t)c * chan4] = t;
        }
    }
}

extern "C" void kernel_launch(void* const* d_in, const int* in_sizes, int n_in,
                              void* d_out, int out_size, void* d_ws, size_t ws_size,
                              hipStream_t stream) {
    const float* img = (const float*)d_in[0];
    const int* cy    = (const int*)d_in[1];
    const int* cx    = (const int*)d_in[2];
    const int* rr    = (const int*)d_in[3];
    float* out       = (float*)d_out;

    const int blocks = N_IMG * (H_DIM / ROWS_PER_BLK);   // 1024
    dust_kernel<<<blocks, THREADS, 0, stream>>>(img, cy, cx, rr, out);
}